// Round 25
// baseline (129.339 us; speedup 1.0000x reference)
//
#include <hip/hip_runtime.h>

static constexpr int IN_C  = 128;
static constexpr int HID   = 96;
static constexpr int OUT_C = 48;

static constexpr int NPART     = 8;
static constexpr int FILL_ITER = 16;
static constexpr int CHUNK     = 256 * FILL_ITER;
static constexpr int CAP       = 64;    // max in-degree slots (Poisson(16): P(>=64)~2e-18)

typedef short bf16x8 __attribute__((ext_vector_type(8)));
typedef float f32x4  __attribute__((ext_vector_type(4)));

// ---------------- bf16 helpers ----------------

__device__ __forceinline__ unsigned short f2bf(float f) {   // RNE pack
  union { float f; unsigned u; } c; c.f = f;
  unsigned r = c.u + 0x7fffu + ((c.u >> 16) & 1u);
  return (unsigned short)(r >> 16);
}
__device__ __forceinline__ float bflo(unsigned u) {
  union { unsigned u; float f; } c; c.u = u << 16; return c.f;
}
__device__ __forceinline__ float bfhi(unsigned u) {
  union { unsigned u; float f; } c; c.u = u & 0xffff0000u; return c.f;
}

// Pre-pack W (fp32 row-major [K][M]) into B-fragment order for 16x16x32 MFMA.
__device__ __forceinline__ void wprep_one(const float* W, uint4* Wt,
                                          int K, int M, int idx) {
  int lane = idx & 63;
  int t = idx >> 6;
  int KB = K / 32;
  int c  = t / KB;
  int kb = t - c * KB;
  int col = c * 16 + (lane & 15);
  int k0  = kb * 32 + (lane >> 4) * 8;
  unsigned pk[4];
#pragma unroll
  for (int q = 0; q < 4; ++q) {
    unsigned lo = f2bf(W[(size_t)(k0 + 2 * q) * M + col]);
    unsigned hi = f2bf(W[(size_t)(k0 + 2 * q + 1) * M + col]);
    pk[q] = lo | (hi << 16);
  }
  Wt[idx] = make_uint4(pk[0], pk[1], pk[2], pk[3]);
}

// fused: zero cnt + pack both weight matrices (one launch)
__global__ void k_init(int* __restrict__ cnt, int n, int nbN,
                       const float* __restrict__ W1, uint4* __restrict__ Wt1, int T1,
                       const float* __restrict__ W2, uint4* __restrict__ Wt2, int T2) {
  int b = blockIdx.x;
  if (b < nbN) {
    int i = b * 256 + threadIdx.x;
    if (i < n) cnt[i] = 0;
  } else {
    int idx = (b - nbN) * 256 + threadIdx.x;
    if (idx < T1) wprep_one(W1, Wt1, IN_C, HID, idx);
    else if (idx < T1 + T2) wprep_one(W2, Wt2, HID, OUT_C, idx - T1);
  }
}

// ---------------- gemm body (shared) ----------------

template <int K, int M, bool ABF16, bool NT>
__device__ __forceinline__ void gemm_stage(const void* __restrict__ Xv,
                                           int N, int base,
                                           unsigned short* lds, int tid) {
  constexpr int GR = K / 8;
  for (int idx = tid; idx < 64 * GR; idx += 256) {
    int row = idx / GR;
    int g   = idx - row * GR;
    int srow = min(base + row, N - 1);
    uint4 pk;
    if (ABF16) {
      pk = *(const uint4*)((const unsigned short*)Xv + (size_t)srow * K + g * 8);
    } else {
      const float* xp = (const float*)Xv + (size_t)srow * K + g * 8;
      f32x4 v0, v1;
      if (NT) {
        v0 = __builtin_nontemporal_load((const f32x4*)xp);
        v1 = __builtin_nontemporal_load((const f32x4*)(xp + 4));
      } else {
        v0 = *(const f32x4*)xp;
        v1 = *(const f32x4*)(xp + 4);
      }
      pk.x = (unsigned)f2bf(v0[0]) | ((unsigned)f2bf(v0[1]) << 16);
      pk.y = (unsigned)f2bf(v0[2]) | ((unsigned)f2bf(v0[3]) << 16);
      pk.z = (unsigned)f2bf(v1[0]) | ((unsigned)f2bf(v1[1]) << 16);
      pk.w = (unsigned)f2bf(v1[2]) | ((unsigned)f2bf(v1[3]) << 16);
    }
    int gs = g ^ (row & 7);
    *(uint4*)(&lds[row * 128 + gs * 8]) = pk;
  }
}

template <int K, int M, bool SCALE>
__device__ __forceinline__ void gemm_compute(const uint4* __restrict__ Wt,
                                             const float* __restrict__ dinv,
                                             unsigned short* __restrict__ Y,
                                             int N, int base,
                                             const unsigned short* lds, int tid) {
  constexpr int KB = K / 32;
  constexpr int CT = M / 16;
  const int lane = tid & 63;
  const int wv   = tid >> 6;
  const int lrow = wv * 16 + (lane & 15);
  const int khi  = lane >> 4;

  f32x4 acc[CT];
#pragma unroll
  for (int c = 0; c < CT; ++c) acc[c] = (f32x4){0.f, 0.f, 0.f, 0.f};

  const bf16x8* Wb = (const bf16x8*)Wt;
#pragma unroll
  for (int kb = 0; kb < KB; ++kb) {
    int j  = khi + kb * 4;
    int js = j ^ (lrow & 7);
    bf16x8 a = *(const bf16x8*)(&lds[lrow * 128 + js * 8]);
#pragma unroll
    for (int c = 0; c < CT; ++c) {
      bf16x8 b = Wb[(c * KB + kb) * 64 + lane];
      acc[c] = __builtin_amdgcn_mfma_f32_16x16x32_bf16(a, b, acc[c], 0, 0, 0);
    }
  }

  const int r0 = base + wv * 16 + khi * 4;
#pragma unroll
  for (int i = 0; i < 4; ++i) {
    int row = r0 + i;
    if (row < N) {
      float d = SCALE ? dinv[row] : 1.0f;
      unsigned short* yp = Y + (size_t)row * M + (lane & 15);
#pragma unroll
      for (int c = 0; c < CT; ++c) {
        yp[c * 16] = f2bf(SCALE ? acc[c][i] * d : acc[c][i]);
      }
    }
  }
}

// ---------------- fused gemm1 + fixed-cap CSR fill ----------------
// Gemm blocks FIRST (bid < rowBlocks): X streaming (nt-tagged) happens early.
// Fill blocks after: partition = fb&7 (XCD-local csr/cnt writes);
// slot = atomicAdd(cnt[d]); csr[d*CAP+slot] = src[e].
// NEW: dst/src reads in the fill are NON-TEMPORAL — each XCD streams them
// exactly once (zero reuse), so they must not evict the partition's csr/cnt
// lines from L2 (the write-combining working set).

__global__ __launch_bounds__(256) void k_fill_gemm1(
    const int* __restrict__ src, const int* __restrict__ dst,
    int* __restrict__ cnt, int* __restrict__ csr, int E, int P, int rowBlocks,
    const float* __restrict__ X, const uint4* __restrict__ Wt,
    unsigned short* __restrict__ Y, int N) {
  __shared__ unsigned short lds[64 * 128];
  int bid = blockIdx.x;
  if (bid < rowBlocks) {
    gemm_stage<IN_C, HID, false, true>(X, N, bid * 64, lds, threadIdx.x);
    __syncthreads();
    gemm_compute<IN_C, HID, false>(Wt, nullptr, Y, N, bid * 64, lds, threadIdx.x);
    return;
  }
  int fb = bid - rowBlocks;
  int lo = (fb & (NPART - 1)) * P;
  int hi = lo + P;
  int base = (fb >> 3) * CHUNK + threadIdx.x;
#pragma unroll
  for (int i = 0; i < FILL_ITER; ++i) {
    int e = base + i * 256;
    if (e < E) {
      int d = __builtin_nontemporal_load(dst + e);
      if (d >= lo && d < hi) {
        int s = atomicAdd(&cnt[d], 1);
        int v = __builtin_nontemporal_load(src + e);
        if (s < CAP) csr[d * CAP + s] = v;
      }
    }
  }
}

// ---------------- scale pass: dinv = rsqrt(cnt+1); hbf *= dinv ----------------

__global__ __launch_bounds__(256) void k_scale(unsigned short* __restrict__ hbf,
                                               const int* __restrict__ cnt,
                                               float* __restrict__ dinv, int N) {
  constexpr int JC = HID / 8;   // 12
  int gid = blockIdx.x * blockDim.x + threadIdx.x;
  int n = gid / JC;
  if (n >= N) return;
  int f8 = (gid - n * JC) * 8;
  float dn = rsqrtf((float)cnt[n] + 1.0f);
  if (f8 == 0) dinv[n] = dn;
  unsigned short* hp = hbf + (size_t)n * HID + f8;
  uint4 v = *(const uint4*)hp;
  uint4 pk;
  pk.x = (unsigned)f2bf(bflo(v.x) * dn) | ((unsigned)f2bf(bfhi(v.x) * dn) << 16);
  pk.y = (unsigned)f2bf(bflo(v.y) * dn) | ((unsigned)f2bf(bfhi(v.y) * dn) << 16);
  pk.z = (unsigned)f2bf(bflo(v.z) * dn) | ((unsigned)f2bf(bfhi(v.z) * dn) << 16);
  pk.w = (unsigned)f2bf(bflo(v.w) * dn) | ((unsigned)f2bf(bfhi(v.w) * dn) << 16);
  *(uint4*)hp = pk;
}

// ---------------- bf16 accumulate helper ----------------

__device__ __forceinline__ void bfacc(float* a, const uint4& v) {
  a[0] += bflo(v.x); a[1] += bfhi(v.x);
  a[2] += bflo(v.y); a[3] += bfhi(v.y);
  a[4] += bflo(v.z); a[5] += bfhi(v.z);
  a[6] += bflo(v.w); a[7] += bfhi(v.w);
}

// ---------------- fused agg1 + gemm2 (fixed-cap, 4-edge unroll) ----------------

__global__ __launch_bounds__(256) void k_agg1_gemm2(
    const unsigned short* __restrict__ Hs,   // hbf, dinv-prescaled by k_scale
    const int* __restrict__ csr, const int* __restrict__ cnt,
    const float* __restrict__ dinv, const float* __restrict__ b1,
    const uint4* __restrict__ Wt2, unsigned short* __restrict__ Y, int N) {
  __shared__ unsigned short lds[64 * 128];
  const int tid  = threadIdx.x;
  const int base = blockIdx.x * 64;
  const int nl   = tid >> 2;          // node_local 0..63
  const int fq   = tid & 3;           // feature quarter (24 feats)
  const int n    = base + nl;
  const int f0   = fq * 24;

  unsigned pk[12];
  if (n < N) {
    float dn = dinv[n];
    float a[24];
#pragma unroll
    for (int q = 0; q < 24; ++q) a[q] = 0.f;
    const unsigned short* hp = Hs + (size_t)n * HID + f0;
    uint4 s0 = *(const uint4*)(hp);
    uint4 s1 = *(const uint4*)(hp + 8);
    uint4 s2 = *(const uint4*)(hp + 16);
    bfacc(a, s0); bfacc(a + 8, s1); bfacc(a + 16, s2);
    int p = n * CAP;
    int e = min(cnt[n], CAP);
    int i = 0;
    for (; i + 4 <= e; i += 4) {
      int q0 = csr[p + i];
      int q1 = csr[p + i + 1];
      int q2 = csr[p + i + 2];
      int q3 = csr[p + i + 3];
      const unsigned short* g0 = Hs + (size_t)q0 * HID + f0;
      const unsigned short* g1 = Hs + (size_t)q1 * HID + f0;
      const unsigned short* g2 = Hs + (size_t)q2 * HID + f0;
      const unsigned short* g3 = Hs + (size_t)q3 * HID + f0;
      uint4 u0 = *(const uint4*)(g0);
      uint4 u1 = *(const uint4*)(g0 + 8);
      uint4 u2 = *(const uint4*)(g0 + 16);
      uint4 v0 = *(const uint4*)(g1);
      uint4 v1 = *(const uint4*)(g1 + 8);
      uint4 v2 = *(const uint4*)(g1 + 16);
      uint4 w0 = *(const uint4*)(g2);
      uint4 w1 = *(const uint4*)(g2 + 8);
      uint4 w2 = *(const uint4*)(g2 + 16);
      uint4 x0 = *(const uint4*)(g3);
      uint4 x1 = *(const uint4*)(g3 + 8);
      uint4 x2 = *(const uint4*)(g3 + 16);
      bfacc(a, u0); bfacc(a + 8, u1); bfacc(a + 16, u2);
      bfacc(a, v0); bfacc(a + 8, v1); bfacc(a + 16, v2);
      bfacc(a, w0); bfacc(a + 8, w1); bfacc(a + 16, w2);
      bfacc(a, x0); bfacc(a + 8, x1); bfacc(a + 16, x2);
    }
    for (; i < e; ++i) {
      int q0 = csr[p + i];
      const unsigned short* g0 = Hs + (size_t)q0 * HID + f0;
      uint4 u0 = *(const uint4*)(g0);
      uint4 u1 = *(const uint4*)(g0 + 8);
      uint4 u2 = *(const uint4*)(g0 + 16);
      bfacc(a, u0); bfacc(a + 8, u1); bfacc(a + 16, u2);
    }
#pragma unroll
    for (int q = 0; q < 24; q += 2) {
      float r0 = fmaxf(fmaf(dn, a[q],     b1[f0 + q]),     0.0f);
      float r1 = fmaxf(fmaf(dn, a[q + 1], b1[f0 + q + 1]), 0.0f);
      pk[q / 2] = (unsigned)f2bf(r0) | ((unsigned)f2bf(r1) << 16);
    }
  } else {
#pragma unroll
    for (int q = 0; q < 12; ++q) pk[q] = 0;
  }
  // write 3 granules (8 feats) into swizzled A-tile layout
#pragma unroll
  for (int j = 0; j < 3; ++j) {
    int g  = fq * 3 + j;
    int gs = g ^ (nl & 7);
    *(uint4*)(&lds[nl * 128 + gs * 8]) = *(uint4*)(&pk[j * 4]);
  }
  __syncthreads();
  gemm_compute<HID, OUT_C, true>(Wt2, dinv, Y, N, base, lds, tid);
}

// ---------------- Aggregation layer 2 (fixed-cap, fp32 out) ----------------

__global__ __launch_bounds__(256) void k_agg2(const unsigned short* __restrict__ Hs,
                                              const int* __restrict__ csr,
                                              const int* __restrict__ cnt,
                                              const float* __restrict__ dinv,
                                              const float* __restrict__ bias,
                                              float* __restrict__ out, int N) {
  constexpr int M = OUT_C;
  constexpr int JC = M / 8;
  int gid = blockIdx.x * blockDim.x + threadIdx.x;
  int n = gid / JC;
  if (n >= N) return;
  int f8 = (gid - n * JC) * 8;
  float dn = dinv[n];
  float a[8] = {};
  {
    uint4 sv = *(const uint4*)(Hs + (size_t)n * M + f8);
    bfacc(a, sv);
  }
  int p = n * CAP;
  int e = min(cnt[n], CAP);
  int i = 0;
  for (; i + 8 <= e; i += 8) {
    int s0 = csr[p + i];
    int s1 = csr[p + i + 1];
    int s2 = csr[p + i + 2];
    int s3 = csr[p + i + 3];
    int s4 = csr[p + i + 4];
    int s5 = csr[p + i + 5];
    int s6 = csr[p + i + 6];
    int s7 = csr[p + i + 7];
    uint4 g0 = *(const uint4*)(Hs + (size_t)s0 * M + f8);
    uint4 g1 = *(const uint4*)(Hs + (size_t)s1 * M + f8);
    uint4 g2 = *(const uint4*)(Hs + (size_t)s2 * M + f8);
    uint4 g3 = *(const uint4*)(Hs + (size_t)s3 * M + f8);
    uint4 g4 = *(const uint4*)(Hs + (size_t)s4 * M + f8);
    uint4 g5 = *(const uint4*)(Hs + (size_t)s5 * M + f8);
    uint4 g6 = *(const uint4*)(Hs + (size_t)s6 * M + f8);
    uint4 g7 = *(const uint4*)(Hs + (size_t)s7 * M + f8);
    bfacc(a, g0); bfacc(a, g1); bfacc(a, g2); bfacc(a, g3);
    bfacc(a, g4); bfacc(a, g5); bfacc(a, g6); bfacc(a, g7);
  }
  for (; i + 4 <= e; i += 4) {
    int s0 = csr[p + i];
    int s1 = csr[p + i + 1];
    int s2 = csr[p + i + 2];
    int s3 = csr[p + i + 3];
    uint4 g0 = *(const uint4*)(Hs + (size_t)s0 * M + f8);
    uint4 g1 = *(const uint4*)(Hs + (size_t)s1 * M + f8);
    uint4 g2 = *(const uint4*)(Hs + (size_t)s2 * M + f8);
    uint4 g3 = *(const uint4*)(Hs + (size_t)s3 * M + f8);
    bfacc(a, g0); bfacc(a, g1); bfacc(a, g2); bfacc(a, g3);
  }
  for (; i < e; ++i) {
    int s = csr[p + i];
    uint4 g = *(const uint4*)(Hs + (size_t)s * M + f8);
    bfacc(a, g);
  }
  float4 r0, r1;
  r0.x = fmaf(dn, a[0], bias[f8 + 0]);
  r0.y = fmaf(dn, a[1], bias[f8 + 1]);
  r0.z = fmaf(dn, a[2], bias[f8 + 2]);
  r0.w = fmaf(dn, a[3], bias[f8 + 3]);
  r1.x = fmaf(dn, a[4], bias[f8 + 4]);
  r1.y = fmaf(dn, a[5], bias[f8 + 5]);
  r1.z = fmaf(dn, a[6], bias[f8 + 6]);
  r1.w = fmaf(dn, a[7], bias[f8 + 7]);
  float* op = out + (size_t)n * M + f8;
  *(float4*)(op)     = r0;
  *(float4*)(op + 4) = r1;
}

// ---------------- launch ----------------

extern "C" void kernel_launch(void* const* d_in, const int* in_sizes, int n_in,
                              void* d_out, int out_size, void* d_ws, size_t ws_size,
                              hipStream_t stream) {
  const float* x  = (const float*)d_in[0];
  const int*   ei = (const int*)d_in[1];
  const float* W1 = (const float*)d_in[2];
  const float* b1 = (const float*)d_in[3];
  const float* W2 = (const float*)d_in[4];
  const float* b2 = (const float*)d_in[5];
  float* out = (float*)d_out;

  const int N = in_sizes[0] / IN_C;     // 50000
  const int E = in_sizes[1] / 2;        // 800000
  const int* src = ei;
  const int* dst = ei + E;

  char* ws = (char*)d_ws;
  size_t off = 0;
  auto alloc = [&](size_t bytes) -> void* {
    void* p = ws + off;
    off = (off + bytes + 255) & ~(size_t)255;
    return p;
  };
  int*   cnt    = (int*)alloc((size_t)N * 4);
  float* dinv   = (float*)alloc((size_t)N * 4);
  int*   csr    = (int*)alloc((size_t)N * CAP * 4);                  // 12.8 MB
  unsigned short* hbf = (unsigned short*)alloc((size_t)N * HID * 2); // gemm1 out
  unsigned short* hb2 = (unsigned short*)alloc((size_t)N * HID * 2); // gemm2 out
  constexpr int T1 = (HID / 16) * (IN_C / 32) * 64;   // 1536
  constexpr int T2 = (OUT_C / 16) * (HID / 32) * 64;  // 576
  uint4* Wt1 = (uint4*)alloc((size_t)T1 * 16);
  uint4* Wt2 = (uint4*)alloc((size_t)T2 * 16);

  const int nbN = (N + 255) / 256;      // 196
  const int P   = (N + NPART - 1) / NPART;
  const int wprepBlocks = (T1 + T2 + 255) / 256;
  const int fillBlocks  = NPART * ((E + CHUNK - 1) / CHUNK);   // 1568
  const int rowBlocks   = (N + 63) / 64;                       // 782

  // 1) zero cnt + pack weights
  k_init<<<nbN + wprepBlocks, 256, 0, stream>>>(cnt, N, nbN, W1, Wt1, T1, W2, Wt2, T2);

  // 2) layer-1 GEMM (nt X loads) + fixed-cap CSR build (nt dst/src reads)
  k_fill_gemm1<<<rowBlocks + fillBlocks, 256, 0, stream>>>(
      src, dst, cnt, csr, E, P, rowBlocks, x, Wt1, hbf, N);

  // 3) dinv = rsqrt(cnt+1); hbf *= dinv (stores dinv for epilogues)
  {
    int t = N * (HID / 8);
    k_scale<<<(t + 255) / 256, 256, 0, stream>>>(hbf, cnt, dinv, N);
  }

  // 4) layer-1 aggregation + layer-2 GEMM (hbf -> LDS -> hb2)
  k_agg1_gemm2<<<rowBlocks, 256, 0, stream>>>(hbf, csr, cnt, dinv, b1, Wt2, hb2, N);

  // 5) layer-2 aggregation: out = dinv*agg(hb2) + b2
  {
    int t = N * (OUT_C / 8);
    k_agg2<<<(t + 255) / 256, 256, 0, stream>>>(hb2, csr, cnt, dinv, b2, out, N);
  }
}

// Round 26
// 113.176 us; speedup vs baseline: 1.1428x; 1.1428x over previous
//
#include <hip/hip_runtime.h>

static constexpr int IN_C  = 128;
static constexpr int HID   = 96;
static constexpr int OUT_C = 48;

static constexpr int NPART     = 8;
static constexpr int FILL_ITER = 16;
static constexpr int CHUNK     = 256 * FILL_ITER;
static constexpr int CAP       = 64;    // max in-degree slots (Poisson(16): P(>=64)~2e-18)

typedef short bf16x8 __attribute__((ext_vector_type(8)));
typedef float f32x4  __attribute__((ext_vector_type(4)));

// ---------------- bf16 helpers ----------------

__device__ __forceinline__ unsigned short f2bf(float f) {   // RNE pack
  union { float f; unsigned u; } c; c.f = f;
  unsigned r = c.u + 0x7fffu + ((c.u >> 16) & 1u);
  return (unsigned short)(r >> 16);
}
__device__ __forceinline__ float bflo(unsigned u) {
  union { unsigned u; float f; } c; c.u = u << 16; return c.f;
}
__device__ __forceinline__ float bfhi(unsigned u) {
  union { unsigned u; float f; } c; c.u = u & 0xffff0000u; return c.f;
}

// Pre-pack W (fp32 row-major [K][M]) into B-fragment order for 16x16x32 MFMA.
__device__ __forceinline__ void wprep_one(const float* W, uint4* Wt,
                                          int K, int M, int idx) {
  int lane = idx & 63;
  int t = idx >> 6;
  int KB = K / 32;
  int c  = t / KB;
  int kb = t - c * KB;
  int col = c * 16 + (lane & 15);
  int k0  = kb * 32 + (lane >> 4) * 8;
  unsigned pk[4];
#pragma unroll
  for (int q = 0; q < 4; ++q) {
    unsigned lo = f2bf(W[(size_t)(k0 + 2 * q) * M + col]);
    unsigned hi = f2bf(W[(size_t)(k0 + 2 * q + 1) * M + col]);
    pk[q] = lo | (hi << 16);
  }
  Wt[idx] = make_uint4(pk[0], pk[1], pk[2], pk[3]);
}

// fused: zero cnt + pack both weight matrices (one launch)
__global__ void k_init(int* __restrict__ cnt, int n, int nbN,
                       const float* __restrict__ W1, uint4* __restrict__ Wt1, int T1,
                       const float* __restrict__ W2, uint4* __restrict__ Wt2, int T2) {
  int b = blockIdx.x;
  if (b < nbN) {
    int i = b * 256 + threadIdx.x;
    if (i < n) cnt[i] = 0;
  } else {
    int idx = (b - nbN) * 256 + threadIdx.x;
    if (idx < T1) wprep_one(W1, Wt1, IN_C, HID, idx);
    else if (idx < T1 + T2) wprep_one(W2, Wt2, HID, OUT_C, idx - T1);
  }
}

// ---------------- gemm body (shared) ----------------

template <int K, int M, bool ABF16, bool NT>
__device__ __forceinline__ void gemm_stage(const void* __restrict__ Xv,
                                           int N, int base,
                                           unsigned short* lds, int tid) {
  constexpr int GR = K / 8;
  for (int idx = tid; idx < 64 * GR; idx += 256) {
    int row = idx / GR;
    int g   = idx - row * GR;
    int srow = min(base + row, N - 1);
    uint4 pk;
    if (ABF16) {
      pk = *(const uint4*)((const unsigned short*)Xv + (size_t)srow * K + g * 8);
    } else {
      const float* xp = (const float*)Xv + (size_t)srow * K + g * 8;
      f32x4 v0, v1;
      if (NT) {
        v0 = __builtin_nontemporal_load((const f32x4*)xp);
        v1 = __builtin_nontemporal_load((const f32x4*)(xp + 4));
      } else {
        v0 = *(const f32x4*)xp;
        v1 = *(const f32x4*)(xp + 4);
      }
      pk.x = (unsigned)f2bf(v0[0]) | ((unsigned)f2bf(v0[1]) << 16);
      pk.y = (unsigned)f2bf(v0[2]) | ((unsigned)f2bf(v0[3]) << 16);
      pk.z = (unsigned)f2bf(v1[0]) | ((unsigned)f2bf(v1[1]) << 16);
      pk.w = (unsigned)f2bf(v1[2]) | ((unsigned)f2bf(v1[3]) << 16);
    }
    int gs = g ^ (row & 7);
    *(uint4*)(&lds[row * 128 + gs * 8]) = pk;
  }
}

template <int K, int M, bool SCALE>
__device__ __forceinline__ void gemm_compute(const uint4* __restrict__ Wt,
                                             const float* __restrict__ dinv,
                                             unsigned short* __restrict__ Y,
                                             int N, int base,
                                             const unsigned short* lds, int tid) {
  constexpr int KB = K / 32;
  constexpr int CT = M / 16;
  const int lane = tid & 63;
  const int wv   = tid >> 6;
  const int lrow = wv * 16 + (lane & 15);
  const int khi  = lane >> 4;

  f32x4 acc[CT];
#pragma unroll
  for (int c = 0; c < CT; ++c) acc[c] = (f32x4){0.f, 0.f, 0.f, 0.f};

  const bf16x8* Wb = (const bf16x8*)Wt;
#pragma unroll
  for (int kb = 0; kb < KB; ++kb) {
    int j  = khi + kb * 4;
    int js = j ^ (lrow & 7);
    bf16x8 a = *(const bf16x8*)(&lds[lrow * 128 + js * 8]);
#pragma unroll
    for (int c = 0; c < CT; ++c) {
      bf16x8 b = Wb[(c * KB + kb) * 64 + lane];
      acc[c] = __builtin_amdgcn_mfma_f32_16x16x32_bf16(a, b, acc[c], 0, 0, 0);
    }
  }

  const int r0 = base + wv * 16 + khi * 4;
#pragma unroll
  for (int i = 0; i < 4; ++i) {
    int row = r0 + i;
    if (row < N) {
      float d = SCALE ? dinv[row] : 1.0f;
      unsigned short* yp = Y + (size_t)row * M + (lane & 15);
#pragma unroll
      for (int c = 0; c < CT; ++c) {
        yp[c * 16] = f2bf(SCALE ? acc[c][i] * d : acc[c][i]);
      }
    }
  }
}

// ---------------- fused gemm1 + fixed-cap CSR fill (round-22 proven) ----------------
// Gemm blocks FIRST (bid < rowBlocks): X streaming (nt-tagged) happens early.
// Fill blocks after: partition = fb&7 (XCD-local csr/cnt writes);
// slot = atomicAdd(cnt[d]); csr[d*CAP+slot] = src[e].

__global__ __launch_bounds__(256) void k_fill_gemm1(
    const int* __restrict__ src, const int* __restrict__ dst,
    int* __restrict__ cnt, int* __restrict__ csr, int E, int P, int rowBlocks,
    const float* __restrict__ X, const uint4* __restrict__ Wt,
    unsigned short* __restrict__ Y, int N) {
  __shared__ unsigned short lds[64 * 128];
  int bid = blockIdx.x;
  if (bid < rowBlocks) {
    gemm_stage<IN_C, HID, false, true>(X, N, bid * 64, lds, threadIdx.x);
    __syncthreads();
    gemm_compute<IN_C, HID, false>(Wt, nullptr, Y, N, bid * 64, lds, threadIdx.x);
    return;
  }
  int fb = bid - rowBlocks;
  int lo = (fb & (NPART - 1)) * P;
  int hi = lo + P;
  int base = (fb >> 3) * CHUNK + threadIdx.x;
#pragma unroll
  for (int i = 0; i < FILL_ITER; ++i) {
    int e = base + i * 256;
    if (e < E) {
      int d = dst[e];
      if (d >= lo && d < hi) {
        int s = atomicAdd(&cnt[d], 1);
        if (s < CAP) csr[d * CAP + s] = src[e];
      }
    }
  }
}

// ---------------- scale pass: dinv = rsqrt(cnt+1); hbf *= dinv ----------------

__global__ __launch_bounds__(256) void k_scale(unsigned short* __restrict__ hbf,
                                               const int* __restrict__ cnt,
                                               float* __restrict__ dinv, int N) {
  constexpr int JC = HID / 8;   // 12
  int gid = blockIdx.x * blockDim.x + threadIdx.x;
  int n = gid / JC;
  if (n >= N) return;
  int f8 = (gid - n * JC) * 8;
  float dn = rsqrtf((float)cnt[n] + 1.0f);
  if (f8 == 0) dinv[n] = dn;
  unsigned short* hp = hbf + (size_t)n * HID + f8;
  uint4 v = *(const uint4*)hp;
  uint4 pk;
  pk.x = (unsigned)f2bf(bflo(v.x) * dn) | ((unsigned)f2bf(bfhi(v.x) * dn) << 16);
  pk.y = (unsigned)f2bf(bflo(v.y) * dn) | ((unsigned)f2bf(bfhi(v.y) * dn) << 16);
  pk.z = (unsigned)f2bf(bflo(v.z) * dn) | ((unsigned)f2bf(bfhi(v.z) * dn) << 16);
  pk.w = (unsigned)f2bf(bflo(v.w) * dn) | ((unsigned)f2bf(bfhi(v.w) * dn) << 16);
  *(uint4*)hp = pk;
}

// ---------------- bf16 accumulate helper ----------------

__device__ __forceinline__ void bfacc(float* a, const uint4& v) {
  a[0] += bflo(v.x); a[1] += bfhi(v.x);
  a[2] += bflo(v.y); a[3] += bfhi(v.y);
  a[4] += bflo(v.z); a[5] += bfhi(v.z);
  a[6] += bflo(v.w); a[7] += bfhi(v.w);
}

// ---------------- fused agg1 + gemm2 (fixed-cap, 4-edge unroll) ----------------

__global__ __launch_bounds__(256) void k_agg1_gemm2(
    const unsigned short* __restrict__ Hs,   // hbf, dinv-prescaled by k_scale
    const int* __restrict__ csr, const int* __restrict__ cnt,
    const float* __restrict__ dinv, const float* __restrict__ b1,
    const uint4* __restrict__ Wt2, unsigned short* __restrict__ Y, int N) {
  __shared__ unsigned short lds[64 * 128];
  const int tid  = threadIdx.x;
  const int base = blockIdx.x * 64;
  const int nl   = tid >> 2;          // node_local 0..63
  const int fq   = tid & 3;           // feature quarter (24 feats)
  const int n    = base + nl;
  const int f0   = fq * 24;

  unsigned pk[12];
  if (n < N) {
    float dn = dinv[n];
    float a[24];
#pragma unroll
    for (int q = 0; q < 24; ++q) a[q] = 0.f;
    const unsigned short* hp = Hs + (size_t)n * HID + f0;
    uint4 s0 = *(const uint4*)(hp);
    uint4 s1 = *(const uint4*)(hp + 8);
    uint4 s2 = *(const uint4*)(hp + 16);
    bfacc(a, s0); bfacc(a + 8, s1); bfacc(a + 16, s2);
    int p = n * CAP;
    int e = min(cnt[n], CAP);
    int i = 0;
    for (; i + 4 <= e; i += 4) {
      int q0 = csr[p + i];
      int q1 = csr[p + i + 1];
      int q2 = csr[p + i + 2];
      int q3 = csr[p + i + 3];
      const unsigned short* g0 = Hs + (size_t)q0 * HID + f0;
      const unsigned short* g1 = Hs + (size_t)q1 * HID + f0;
      const unsigned short* g2 = Hs + (size_t)q2 * HID + f0;
      const unsigned short* g3 = Hs + (size_t)q3 * HID + f0;
      uint4 u0 = *(const uint4*)(g0);
      uint4 u1 = *(const uint4*)(g0 + 8);
      uint4 u2 = *(const uint4*)(g0 + 16);
      uint4 v0 = *(const uint4*)(g1);
      uint4 v1 = *(const uint4*)(g1 + 8);
      uint4 v2 = *(const uint4*)(g1 + 16);
      uint4 w0 = *(const uint4*)(g2);
      uint4 w1 = *(const uint4*)(g2 + 8);
      uint4 w2 = *(const uint4*)(g2 + 16);
      uint4 x0 = *(const uint4*)(g3);
      uint4 x1 = *(const uint4*)(g3 + 8);
      uint4 x2 = *(const uint4*)(g3 + 16);
      bfacc(a, u0); bfacc(a + 8, u1); bfacc(a + 16, u2);
      bfacc(a, v0); bfacc(a + 8, v1); bfacc(a + 16, v2);
      bfacc(a, w0); bfacc(a + 8, w1); bfacc(a + 16, w2);
      bfacc(a, x0); bfacc(a + 8, x1); bfacc(a + 16, x2);
    }
    for (; i < e; ++i) {
      int q0 = csr[p + i];
      const unsigned short* g0 = Hs + (size_t)q0 * HID + f0;
      uint4 u0 = *(const uint4*)(g0);
      uint4 u1 = *(const uint4*)(g0 + 8);
      uint4 u2 = *(const uint4*)(g0 + 16);
      bfacc(a, u0); bfacc(a + 8, u1); bfacc(a + 16, u2);
    }
#pragma unroll
    for (int q = 0; q < 24; q += 2) {
      float r0 = fmaxf(fmaf(dn, a[q],     b1[f0 + q]),     0.0f);
      float r1 = fmaxf(fmaf(dn, a[q + 1], b1[f0 + q + 1]), 0.0f);
      pk[q / 2] = (unsigned)f2bf(r0) | ((unsigned)f2bf(r1) << 16);
    }
  } else {
#pragma unroll
    for (int q = 0; q < 12; ++q) pk[q] = 0;
  }
  // write 3 granules (8 feats) into swizzled A-tile layout
#pragma unroll
  for (int j = 0; j < 3; ++j) {
    int g  = fq * 3 + j;
    int gs = g ^ (nl & 7);
    *(uint4*)(&lds[nl * 128 + gs * 8]) = *(uint4*)(&pk[j * 4]);
  }
  __syncthreads();
  gemm_compute<HID, OUT_C, true>(Wt2, dinv, Y, N, base, lds, tid);
}

// ---------------- Aggregation layer 2 (fixed-cap, fp32 out) ----------------

__global__ __launch_bounds__(256) void k_agg2(const unsigned short* __restrict__ Hs,
                                              const int* __restrict__ csr,
                                              const int* __restrict__ cnt,
                                              const float* __restrict__ dinv,
                                              const float* __restrict__ bias,
                                              float* __restrict__ out, int N) {
  constexpr int M = OUT_C;
  constexpr int JC = M / 8;
  int gid = blockIdx.x * blockDim.x + threadIdx.x;
  int n = gid / JC;
  if (n >= N) return;
  int f8 = (gid - n * JC) * 8;
  float dn = dinv[n];
  float a[8] = {};
  {
    uint4 sv = *(const uint4*)(Hs + (size_t)n * M + f8);
    bfacc(a, sv);
  }
  int p = n * CAP;
  int e = min(cnt[n], CAP);
  int i = 0;
  for (; i + 8 <= e; i += 8) {
    int s0 = csr[p + i];
    int s1 = csr[p + i + 1];
    int s2 = csr[p + i + 2];
    int s3 = csr[p + i + 3];
    int s4 = csr[p + i + 4];
    int s5 = csr[p + i + 5];
    int s6 = csr[p + i + 6];
    int s7 = csr[p + i + 7];
    uint4 g0 = *(const uint4*)(Hs + (size_t)s0 * M + f8);
    uint4 g1 = *(const uint4*)(Hs + (size_t)s1 * M + f8);
    uint4 g2 = *(const uint4*)(Hs + (size_t)s2 * M + f8);
    uint4 g3 = *(const uint4*)(Hs + (size_t)s3 * M + f8);
    uint4 g4 = *(const uint4*)(Hs + (size_t)s4 * M + f8);
    uint4 g5 = *(const uint4*)(Hs + (size_t)s5 * M + f8);
    uint4 g6 = *(const uint4*)(Hs + (size_t)s6 * M + f8);
    uint4 g7 = *(const uint4*)(Hs + (size_t)s7 * M + f8);
    bfacc(a, g0); bfacc(a, g1); bfacc(a, g2); bfacc(a, g3);
    bfacc(a, g4); bfacc(a, g5); bfacc(a, g6); bfacc(a, g7);
  }
  for (; i + 4 <= e; i += 4) {
    int s0 = csr[p + i];
    int s1 = csr[p + i + 1];
    int s2 = csr[p + i + 2];
    int s3 = csr[p + i + 3];
    uint4 g0 = *(const uint4*)(Hs + (size_t)s0 * M + f8);
    uint4 g1 = *(const uint4*)(Hs + (size_t)s1 * M + f8);
    uint4 g2 = *(const uint4*)(Hs + (size_t)s2 * M + f8);
    uint4 g3 = *(const uint4*)(Hs + (size_t)s3 * M + f8);
    bfacc(a, g0); bfacc(a, g1); bfacc(a, g2); bfacc(a, g3);
  }
  for (; i < e; ++i) {
    int s = csr[p + i];
    uint4 g = *(const uint4*)(Hs + (size_t)s * M + f8);
    bfacc(a, g);
  }
  float4 r0, r1;
  r0.x = fmaf(dn, a[0], bias[f8 + 0]);
  r0.y = fmaf(dn, a[1], bias[f8 + 1]);
  r0.z = fmaf(dn, a[2], bias[f8 + 2]);
  r0.w = fmaf(dn, a[3], bias[f8 + 3]);
  r1.x = fmaf(dn, a[4], bias[f8 + 4]);
  r1.y = fmaf(dn, a[5], bias[f8 + 5]);
  r1.z = fmaf(dn, a[6], bias[f8 + 6]);
  r1.w = fmaf(dn, a[7], bias[f8 + 7]);
  float* op = out + (size_t)n * M + f8;
  *(float4*)(op)     = r0;
  *(float4*)(op + 4) = r1;
}

// ---------------- launch ----------------

extern "C" void kernel_launch(void* const* d_in, const int* in_sizes, int n_in,
                              void* d_out, int out_size, void* d_ws, size_t ws_size,
                              hipStream_t stream) {
  const float* x  = (const float*)d_in[0];
  const int*   ei = (const int*)d_in[1];
  const float* W1 = (const float*)d_in[2];
  const float* b1 = (const float*)d_in[3];
  const float* W2 = (const float*)d_in[4];
  const float* b2 = (const float*)d_in[5];
  float* out = (float*)d_out;

  const int N = in_sizes[0] / IN_C;     // 50000
  const int E = in_sizes[1] / 2;        // 800000
  const int* src = ei;
  const int* dst = ei + E;

  char* ws = (char*)d_ws;
  size_t off = 0;
  auto alloc = [&](size_t bytes) -> void* {
    void* p = ws + off;
    off = (off + bytes + 255) & ~(size_t)255;
    return p;
  };
  int*   cnt    = (int*)alloc((size_t)N * 4);
  float* dinv   = (float*)alloc((size_t)N * 4);
  int*   csr    = (int*)alloc((size_t)N * CAP * 4);                  // 12.8 MB
  unsigned short* hbf = (unsigned short*)alloc((size_t)N * HID * 2); // gemm1 out
  unsigned short* hb2 = (unsigned short*)alloc((size_t)N * HID * 2); // gemm2 out
  constexpr int T1 = (HID / 16) * (IN_C / 32) * 64;   // 1536
  constexpr int T2 = (OUT_C / 16) * (HID / 32) * 64;  // 576
  uint4* Wt1 = (uint4*)alloc((size_t)T1 * 16);
  uint4* Wt2 = (uint4*)alloc((size_t)T2 * 16);

  const int nbN = (N + 255) / 256;      // 196
  const int P   = (N + NPART - 1) / NPART;
  const int wprepBlocks = (T1 + T2 + 255) / 256;
  const int fillBlocks  = NPART * ((E + CHUNK - 1) / CHUNK);   // 1568
  const int rowBlocks   = (N + 63) / 64;                       // 782

  // 1) zero cnt + pack weights
  k_init<<<nbN + wprepBlocks, 256, 0, stream>>>(cnt, N, nbN, W1, Wt1, T1, W2, Wt2, T2);

  // 2) layer-1 GEMM (nt X loads) + fixed-cap CSR build (gemm blocks first)
  k_fill_gemm1<<<rowBlocks + fillBlocks, 256, 0, stream>>>(
      src, dst, cnt, csr, E, P, rowBlocks, x, Wt1, hbf, N);

  // 3) dinv = rsqrt(cnt+1); hbf *= dinv (stores dinv for epilogues)
  {
    int t = N * (HID / 8);
    k_scale<<<(t + 255) / 256, 256, 0, stream>>>(hbf, cnt, dinv, N);
  }

  // 4) layer-1 aggregation + layer-2 GEMM (hbf -> LDS -> hb2)
  k_agg1_gemm2<<<rowBlocks, 256, 0, stream>>>(hbf, csr, cnt, dinv, b1, Wt2, hb2, N);

  // 5) layer-2 aggregation: out = dinv*agg(hb2) + b2
  {
    int t = N * (OUT_C / 8);
    k_agg2<<<(t + 255) / 256, 256, 0, stream>>>(hb2, csr, cnt, dinv, b2, out, N);
  }
}